// Round 1
// baseline (206.623 us; speedup 1.0000x reference)
//
#include <hip/hip_runtime.h>
#include <math.h>

#define H   2048
#define SW  256
#define SD  200
#define GIN (H + SW)   // 2304
#define G3H (3 * H)    // 6144
#define OO  128

// ws float offsets
#define CTRL_OFF 0
#define STOP_OFF 8
#define GI_OFF   512
#define GH_OFF   (GI_OFF + G3H)   // 6656; total ws use = (6656+6144)*4 = 51.2 KB

__device__ __forceinline__ float wave_reduce(float v) {
#pragma unroll
    for (int off = 32; off > 0; off >>= 1)
        v += __shfl_down(v, off, 64);
    return v;
}

__device__ __forceinline__ float sigmoidf(float x) {
    return 1.f / (1.f + expf(-x));
}

// K1: ctrl = softmax(hidden @ Wc^T + bc) -> ws[CTRL_OFF..+3)
__global__ void k_ctrl(const float* __restrict__ hidden,
                       const float* __restrict__ Wc,
                       const float* __restrict__ bc,
                       float* __restrict__ ws) {
    int lane = threadIdx.x;  // 64 threads, 1 wave
    float c0 = 0.f, c1 = 0.f, c2 = 0.f;
    for (int k = lane; k < H; k += 64) {
        float hv = hidden[k];
        c0 += hv * Wc[0 * H + k];
        c1 += hv * Wc[1 * H + k];
        c2 += hv * Wc[2 * H + k];
    }
    c0 = wave_reduce(c0); c1 = wave_reduce(c1); c2 = wave_reduce(c2);
    if (lane == 0) {
        c0 += bc[0]; c1 += bc[1]; c2 += bc[2];
        float m = fmaxf(c0, fmaxf(c1, c2));
        float e0 = expf(c0 - m), e1 = expf(c1 - m), e2 = expf(c2 - m);
        float inv = 1.f / (e0 + e1 + e2);
        ws[CTRL_OFF + 0] = e0 * inv;  // push
        ws[CTRL_OFF + 1] = e1 * inv;  // pop
        ws[CTRL_OFF + 2] = e2 * inv;  // noop
    }
}

// K2: s_in = tanh(hidden @ Ws^T + bs); new_stack; stack_top -> ws
// blocks 0..7: s_in rows (32/block, 8/wave) + new_stack row 0
// blocks 8..57: new_stack rows 1..199 elementwise
__global__ __launch_bounds__(256) void k_stack(
        const float* __restrict__ hidden,
        const float* __restrict__ stack,
        const float* __restrict__ Ws,
        const float* __restrict__ bs,
        float* __restrict__ ws,
        float* __restrict__ out_stack /* d_out + OO + H */) {
    float a_push = ws[CTRL_OFF + 0];
    float a_pop  = ws[CTRL_OFF + 1];
    float a_noop = ws[CTRL_OFF + 2];
    int b = blockIdx.x;
    if (b < 8) {
        int wave = threadIdx.x >> 6, lane = threadIdx.x & 63;
        const float4* h4 = (const float4*)hidden;
#pragma unroll
        for (int r = 0; r < 8; ++r) {
            int row = b * 32 + wave * 8 + r;           // s_in element index in [0,256)
            const float4* w4 = (const float4*)(Ws + row * H);
            float sum = 0.f;
#pragma unroll
            for (int i = 0; i < 8; ++i) {
                float4 a = h4[lane + i * 64];
                float4 c = w4[lane + i * 64];
                sum += a.x * c.x + a.y * c.y + a.z * c.z + a.w * c.w;
            }
            sum = wave_reduce(sum);
            if (lane == 0) {
                float s = tanhf(sum + bs[row]);
                // new_stack[0][row] = noop*stack[0] + push*s_in + pop*stack[1]
                float top = a_noop * stack[row] + a_push * s + a_pop * stack[SW + row];
                ws[STOP_OFF + row] = top;
                out_stack[row] = top;
            }
        }
    } else {
        int rbase = 1 + (b - 8) * 4;
#pragma unroll
        for (int r = 0; r < 4; ++r) {
            int row = rbase + r;
            if (row >= SD) break;
            int idx = row * SW + threadIdx.x;
            float dn = (row < SD - 1) ? stack[idx + SW] : 0.f;
            out_stack[idx] = a_noop * stack[idx] + a_push * stack[idx - SW] + a_pop * dn;
        }
    }
}

// K3: gi = [emb_row ; stack_top] @ W_ih^T + b_ih  (blocks 0..383)
//     gh = hidden @ W_hh^T + b_hh                 (blocks 384..767)
// 256 thr/block, 1 wave per row, 4 rows per wave, vector staged in LDS.
__global__ __launch_bounds__(256) void k_gemv(
        const float* __restrict__ hidden,
        const float* __restrict__ emb,
        const int* __restrict__ inp,
        const float* __restrict__ W_ih, const float* __restrict__ b_ih,
        const float* __restrict__ W_hh, const float* __restrict__ b_hh,
        float* __restrict__ ws) {
    __shared__ __align__(16) float vec[GIN];
    int b = blockIdx.x;
    int tid = threadIdx.x;
    bool is_gi = (b < 384);
    if (is_gi) {
        int e = inp[0];
        const float* er = emb + (long)e * H;
        for (int k = tid; k < H; k += 256) vec[k] = er[k];
        for (int k = H + tid; k < GIN; k += 256) vec[k] = ws[STOP_OFF + (k - H)];
    } else {
        for (int k = tid; k < H; k += 256) vec[k] = hidden[k];
    }
    __syncthreads();
    int wave = tid >> 6, lane = tid & 63;
    int rbase = (is_gi ? b : b - 384) * 16 + wave * 4;
    const float* W    = is_gi ? W_ih : W_hh;
    const float* bias = is_gi ? b_ih : b_hh;
    int K4 = is_gi ? (GIN / 4) : (H / 4);   // 576 or 512 float4s per row
    float* dst = ws + (is_gi ? GI_OFF : GH_OFF);
    const float4* v4 = (const float4*)vec;
#pragma unroll
    for (int r = 0; r < 4; ++r) {
        int row = rbase + r;
        const float4* w4 = (const float4*)(W + (long)row * (K4 * 4));
        float sum = 0.f;
        for (int i = lane; i < K4; i += 64) {
            float4 a = v4[i];
            float4 c = w4[i];
            sum += a.x * c.x + a.y * c.y + a.z * c.z + a.w * c.w;
        }
        sum = wave_reduce(sum);
        if (lane == 0) dst[row] = sum + bias[row];
    }
}

// K4: gates -> h_new (block 0 writes it) ; out = h_new @ Wd^T + bd
// 32 blocks x 256 thr; each block rebuilds h_new in LDS (cheap), 1 out row/wave.
__global__ __launch_bounds__(256) void k_out(
        const float* __restrict__ hidden,
        const float* __restrict__ Wd, const float* __restrict__ bd,
        const float* __restrict__ ws,
        float* __restrict__ d_out) {
    __shared__ __align__(16) float hn[H];
    int tid = threadIdx.x;
    const float* gi = ws + GI_OFF;
    const float* gh = ws + GH_OFF;
    for (int i = tid; i < H; i += 256) {
        float r = sigmoidf(gi[i] + gh[i]);
        float z = sigmoidf(gi[H + i] + gh[H + i]);
        float n = tanhf(gi[2 * H + i] + r * gh[2 * H + i]);
        float v = (1.f - z) * n + z * hidden[i];
        hn[i] = v;
        if (blockIdx.x == 0) d_out[OO + i] = v;
    }
    __syncthreads();
    int wave = tid >> 6, lane = tid & 63;
    int row = blockIdx.x * 4 + wave;     // 32*4 = 128 rows
    const float4* h4 = (const float4*)hn;
    const float4* w4 = (const float4*)(Wd + (long)row * H);
    float sum = 0.f;
#pragma unroll
    for (int i = 0; i < 8; ++i) {
        float4 a = h4[lane + i * 64];
        float4 c = w4[lane + i * 64];
        sum += a.x * c.x + a.y * c.y + a.z * c.z + a.w * c.w;
    }
    sum = wave_reduce(sum);
    if (lane == 0) d_out[row] = sum + bd[row];
}

extern "C" void kernel_launch(void* const* d_in, const int* in_sizes, int n_in,
                              void* d_out, int out_size, void* d_ws, size_t ws_size,
                              hipStream_t stream) {
    const int*   inp    = (const int*)d_in[0];
    const float* hidden = (const float*)d_in[1];
    const float* stack  = (const float*)d_in[2];
    const float* emb    = (const float*)d_in[3];
    const float* Wc     = (const float*)d_in[4];
    const float* bc     = (const float*)d_in[5];
    const float* Ws     = (const float*)d_in[6];
    const float* bs     = (const float*)d_in[7];
    const float* W_ih   = (const float*)d_in[8];
    const float* b_ih   = (const float*)d_in[9];
    const float* W_hh   = (const float*)d_in[10];
    const float* b_hh   = (const float*)d_in[11];
    const float* Wd     = (const float*)d_in[12];
    const float* bd     = (const float*)d_in[13];
    float* out = (float*)d_out;
    float* ws  = (float*)d_ws;

    k_ctrl<<<1, 64, 0, stream>>>(hidden, Wc, bc, ws);
    k_stack<<<58, 256, 0, stream>>>(hidden, stack, Ws, bs, ws, out + OO + H);
    k_gemv<<<768, 256, 0, stream>>>(hidden, emb, inp, W_ih, b_ih, W_hh, b_hh, ws);
    k_out<<<32, 256, 0, stream>>>(hidden, Wd, bd, ws, out);
}

// Round 2
// 195.567 us; speedup vs baseline: 1.0565x; 1.0565x over previous
//
#include <hip/hip_runtime.h>
#include <math.h>

#define H   2048
#define SW  256
#define SD  200
#define GIN (H + SW)   // 2304
#define G3H (3 * H)    // 6144
#define OO  128

// ws float offsets
#define STOP_OFF 8
#define GI_OFF   512
#define GH_OFF   (GI_OFF + G3H)   // 6656

__device__ __forceinline__ float wave_reduce(float v) {
#pragma unroll
    for (int off = 32; off > 0; off >>= 1)
        v += __shfl_down(v, off, 64);
    return v;
}

__device__ __forceinline__ float sigmoidf(float x) {
    return 1.f / (1.f + expf(-x));
}

// K1: ctrl (computed redundantly per block) + s_in + new_stack + stack_top
// blocks 0..7: s_in rows (32/block, 8/wave) + new_stack row 0
// blocks 8..57: new_stack rows 1..199 elementwise
__global__ __launch_bounds__(256) void k_stack(
        const float* __restrict__ hidden,
        const float* __restrict__ stack,
        const float* __restrict__ Wc,
        const float* __restrict__ bc,
        const float* __restrict__ Ws,
        const float* __restrict__ bs,
        float* __restrict__ ws,
        float* __restrict__ out_stack /* d_out + OO + H */) {
    __shared__ float sc[3];
    int tid = threadIdx.x;
    // ctrl softmax, computed by wave 0 of every block (24 KB read, L2-hit)
    if (tid < 64) {
        float c0 = 0.f, c1 = 0.f, c2 = 0.f;
        for (int k = tid; k < H; k += 64) {
            float hv = hidden[k];
            c0 += hv * Wc[k];
            c1 += hv * Wc[H + k];
            c2 += hv * Wc[2 * H + k];
        }
        c0 = wave_reduce(c0); c1 = wave_reduce(c1); c2 = wave_reduce(c2);
        if (tid == 0) {
            c0 += bc[0]; c1 += bc[1]; c2 += bc[2];
            float m = fmaxf(c0, fmaxf(c1, c2));
            float e0 = expf(c0 - m), e1 = expf(c1 - m), e2 = expf(c2 - m);
            float inv = 1.f / (e0 + e1 + e2);
            sc[0] = e0 * inv;  // push
            sc[1] = e1 * inv;  // pop
            sc[2] = e2 * inv;  // noop
        }
    }
    __syncthreads();
    float a_push = sc[0], a_pop = sc[1], a_noop = sc[2];
    int b = blockIdx.x;
    if (b < 8) {
        int wave = tid >> 6, lane = tid & 63;
        const float4* h4 = (const float4*)hidden;
#pragma unroll
        for (int r = 0; r < 8; ++r) {
            int row = b * 32 + wave * 8 + r;           // s_in element index in [0,256)
            const float4* w4 = (const float4*)(Ws + row * H);
            float sum = 0.f;
#pragma unroll
            for (int i = 0; i < 8; ++i) {
                float4 a = h4[lane + i * 64];
                float4 c = w4[lane + i * 64];
                sum += a.x * c.x + a.y * c.y + a.z * c.z + a.w * c.w;
            }
            sum = wave_reduce(sum);
            if (lane == 0) {
                float s = tanhf(sum + bs[row]);
                float top = a_noop * stack[row] + a_push * s + a_pop * stack[SW + row];
                ws[STOP_OFF + row] = top;
                out_stack[row] = top;
            }
        }
    } else {
        int rbase = 1 + (b - 8) * 4;
#pragma unroll
        for (int r = 0; r < 4; ++r) {
            int row = rbase + r;
            if (row >= SD) break;
            int idx = row * SW + tid;
            float dn = (row < SD - 1) ? stack[idx + SW] : 0.f;
            out_stack[idx] = a_noop * stack[idx] + a_push * stack[idx - SW] + a_pop * dn;
        }
    }
}

// K2: gi = [emb_row ; stack_top] @ W_ih^T + b_ih  (blocks 0..383)
//     gh = hidden @ W_hh^T + b_hh                 (blocks 384..767)
// 256 thr/block, 4 waves, 4 rows/wave with row-interleaved K loop:
// 4 independent float4 load chains per lane for memory-level parallelism.
__global__ __launch_bounds__(256) void k_gemv(
        const float* __restrict__ hidden,
        const float* __restrict__ emb,
        const int* __restrict__ inp,
        const float* __restrict__ W_ih, const float* __restrict__ b_ih,
        const float* __restrict__ W_hh, const float* __restrict__ b_hh,
        float* __restrict__ ws) {
    __shared__ __align__(16) float vec[GIN];
    int b = blockIdx.x;
    int tid = threadIdx.x;
    bool is_gi = (b < 384);
    if (is_gi) {
        int e = inp[0];
        const float* er = emb + (long)e * H;
        for (int k = tid; k < H; k += 256) vec[k] = er[k];
        for (int k = H + tid; k < GIN; k += 256) vec[k] = ws[STOP_OFF + (k - H)];
    } else {
        for (int k = tid; k < H; k += 256) vec[k] = hidden[k];
    }
    __syncthreads();
    int wave = tid >> 6, lane = tid & 63;
    int rbase = (is_gi ? b : b - 384) * 16 + wave * 4;
    const float* W    = is_gi ? W_ih : W_hh;
    const float* bias = is_gi ? b_ih : b_hh;
    int K  = is_gi ? GIN : H;
    int K4 = K >> 2;                       // 576 or 512
    const float4* v4 = (const float4*)vec;
    const float4* w0 = (const float4*)(W + (long)(rbase + 0) * K);
    const float4* w1 = (const float4*)(W + (long)(rbase + 1) * K);
    const float4* w2 = (const float4*)(W + (long)(rbase + 2) * K);
    const float4* w3 = (const float4*)(W + (long)(rbase + 3) * K);
    float s0 = 0.f, s1 = 0.f, s2 = 0.f, s3 = 0.f;
    for (int i = lane; i < K4; i += 64) {
        float4 a  = v4[i];
        float4 b0 = w0[i];
        float4 b1 = w1[i];
        float4 b2 = w2[i];
        float4 b3 = w3[i];
        s0 += a.x * b0.x + a.y * b0.y + a.z * b0.z + a.w * b0.w;
        s1 += a.x * b1.x + a.y * b1.y + a.z * b1.z + a.w * b1.w;
        s2 += a.x * b2.x + a.y * b2.y + a.z * b2.z + a.w * b2.w;
        s3 += a.x * b3.x + a.y * b3.y + a.z * b3.z + a.w * b3.w;
    }
    s0 = wave_reduce(s0);
    s1 = wave_reduce(s1);
    s2 = wave_reduce(s2);
    s3 = wave_reduce(s3);
    float* dst = ws + (is_gi ? GI_OFF : GH_OFF);
    if (lane == 0) {
        dst[rbase + 0] = s0 + bias[rbase + 0];
        dst[rbase + 1] = s1 + bias[rbase + 1];
        dst[rbase + 2] = s2 + bias[rbase + 2];
        dst[rbase + 3] = s3 + bias[rbase + 3];
    }
}

// K3: gates -> h_new (block 0 writes it) ; out = h_new @ Wd^T + bd
__global__ __launch_bounds__(256) void k_out(
        const float* __restrict__ hidden,
        const float* __restrict__ Wd, const float* __restrict__ bd,
        const float* __restrict__ ws,
        float* __restrict__ d_out) {
    __shared__ __align__(16) float hn[H];
    int tid = threadIdx.x;
    const float* gi = ws + GI_OFF;
    const float* gh = ws + GH_OFF;
    for (int i = tid; i < H; i += 256) {
        float r = sigmoidf(gi[i] + gh[i]);
        float z = sigmoidf(gi[H + i] + gh[H + i]);
        float n = tanhf(gi[2 * H + i] + r * gh[2 * H + i]);
        float v = (1.f - z) * n + z * hidden[i];
        hn[i] = v;
        if (blockIdx.x == 0) d_out[OO + i] = v;
    }
    __syncthreads();
    int wave = tid >> 6, lane = tid & 63;
    int row = blockIdx.x * 4 + wave;     // 32*4 = 128 rows
    const float4* h4 = (const float4*)hn;
    const float4* w4 = (const float4*)(Wd + (long)row * H);
    float sum = 0.f;
#pragma unroll
    for (int i = 0; i < 8; ++i) {
        float4 a = h4[lane + i * 64];
        float4 c = w4[lane + i * 64];
        sum += a.x * c.x + a.y * c.y + a.z * c.z + a.w * c.w;
    }
    sum = wave_reduce(sum);
    if (lane == 0) d_out[row] = sum + bd[row];
}

extern "C" void kernel_launch(void* const* d_in, const int* in_sizes, int n_in,
                              void* d_out, int out_size, void* d_ws, size_t ws_size,
                              hipStream_t stream) {
    const int*   inp    = (const int*)d_in[0];
    const float* hidden = (const float*)d_in[1];
    const float* stack  = (const float*)d_in[2];
    const float* emb    = (const float*)d_in[3];
    const float* Wc     = (const float*)d_in[4];
    const float* bc     = (const float*)d_in[5];
    const float* Ws     = (const float*)d_in[6];
    const float* bs     = (const float*)d_in[7];
    const float* W_ih   = (const float*)d_in[8];
    const float* b_ih   = (const float*)d_in[9];
    const float* W_hh   = (const float*)d_in[10];
    const float* b_hh   = (const float*)d_in[11];
    const float* Wd     = (const float*)d_in[12];
    const float* bd     = (const float*)d_in[13];
    float* out = (float*)d_out;
    float* ws  = (float*)d_ws;

    k_stack<<<58, 256, 0, stream>>>(hidden, stack, Wc, bc, Ws, bs, ws, out + OO + H);
    k_gemv<<<768, 256, 0, stream>>>(hidden, emb, inp, W_ih, b_ih, W_hh, b_hh, ws);
    k_out<<<32, 256, 0, stream>>>(hidden, Wd, bd, ws, out);
}

// Round 3
// 179.635 us; speedup vs baseline: 1.1502x; 1.0887x over previous
//
#include <hip/hip_runtime.h>
#include <math.h>

#define H   2048
#define SW  256
#define SD  200
#define GIN (H + SW)   // 2304
#define G3H (3 * H)    // 6144
#define OO  128

// ws float offsets
#define STOP_OFF 8
#define GI_OFF   512
#define GH_OFF   (GI_OFF + G3H)   // 6656

__device__ __forceinline__ float wave_reduce(float v) {
#pragma unroll
    for (int off = 32; off > 0; off >>= 1)
        v += __shfl_down(v, off, 64);
    return v;
}

__device__ __forceinline__ float sigmoidf(float x) {
    return 1.f / (1.f + expf(-x));
}

__device__ __forceinline__ float dot4(float4 a, float4 b) {
    return a.x * b.x + a.y * b.y + a.z * b.z + a.w * b.w;
}

// K1: ctrl (computed redundantly per block) + s_in + new_stack + stack_top
// blocks 0..63:  s_in rows (1 row/wave, 4/block) + new_stack row 0
// blocks 64..113: new_stack rows 1..199 elementwise
__global__ __launch_bounds__(256) void k_stack(
        const float* __restrict__ hidden,
        const float* __restrict__ stack,
        const float* __restrict__ Wc,
        const float* __restrict__ bc,
        const float* __restrict__ Ws,
        const float* __restrict__ bs,
        float* __restrict__ ws,
        float* __restrict__ out_stack /* d_out + OO + H */) {
    __shared__ float sc[3];
    int tid = threadIdx.x;
    // ctrl softmax, computed by wave 0 of every block (24 KB read, L2/L3-hit)
    if (tid < 64) {
        float c0 = 0.f, c1 = 0.f, c2 = 0.f;
        for (int k = tid; k < H; k += 64) {
            float hv = hidden[k];
            c0 += hv * Wc[k];
            c1 += hv * Wc[H + k];
            c2 += hv * Wc[2 * H + k];
        }
        c0 = wave_reduce(c0); c1 = wave_reduce(c1); c2 = wave_reduce(c2);
        if (tid == 0) {
            c0 += bc[0]; c1 += bc[1]; c2 += bc[2];
            float m = fmaxf(c0, fmaxf(c1, c2));
            float e0 = expf(c0 - m), e1 = expf(c1 - m), e2 = expf(c2 - m);
            float inv = 1.f / (e0 + e1 + e2);
            sc[0] = e0 * inv;  // push
            sc[1] = e1 * inv;  // pop
            sc[2] = e2 * inv;  // noop
        }
    }
    __syncthreads();
    float a_push = sc[0], a_pop = sc[1], a_noop = sc[2];
    int b = blockIdx.x;
    if (b < 64) {
        int wave = tid >> 6, lane = tid & 63;
        int row = b * 4 + wave;                    // s_in element index in [0,256)
        const float4* h4 = (const float4*)hidden;
        const float4* w4 = (const float4*)(Ws + row * H);
        float sum = 0.f;
#pragma unroll
        for (int i = 0; i < 8; ++i) {
            float4 a = h4[lane + i * 64];
            float4 c = w4[lane + i * 64];
            sum += dot4(a, c);
        }
        sum = wave_reduce(sum);
        if (lane == 0) {
            float s = tanhf(sum + bs[row]);
            float top = a_noop * stack[row] + a_push * s + a_pop * stack[SW + row];
            ws[STOP_OFF + row] = top;
            out_stack[row] = top;
        }
    } else {
        int rbase = 1 + (b - 64) * 4;
#pragma unroll
        for (int r = 0; r < 4; ++r) {
            int row = rbase + r;
            if (row >= SD) break;
            int idx = row * SW + tid;
            float dn = (row < SD - 1) ? stack[idx + SW] : 0.f;
            out_stack[idx] = a_noop * stack[idx] + a_push * stack[idx - SW] + a_pop * dn;
        }
    }
}

// K2: gi = [emb_row ; stack_top] @ W_ih^T + b_ih  (blocks 0..383)
//     gh = hidden @ W_hh^T + b_hh                 (blocks 384..767)
// 4 rows/wave, K-loop unrolled x2: 8 independent float4 weight loads in
// flight per lane (8 KB/wave outstanding) -> memory-level parallelism.
__global__ __launch_bounds__(256) void k_gemv(
        const float* __restrict__ hidden,
        const float* __restrict__ emb,
        const int* __restrict__ inp,
        const float* __restrict__ W_ih, const float* __restrict__ b_ih,
        const float* __restrict__ W_hh, const float* __restrict__ b_hh,
        float* __restrict__ ws) {
    __shared__ __align__(16) float vec[GIN];
    int b = blockIdx.x;
    int tid = threadIdx.x;
    bool is_gi = (b < 384);
    if (is_gi) {
        int e = inp[0];
        const float* er = emb + (long)e * H;
        for (int k = tid; k < H; k += 256) vec[k] = er[k];
        for (int k = H + tid; k < GIN; k += 256) vec[k] = ws[STOP_OFF + (k - H)];
    } else {
        for (int k = tid; k < H; k += 256) vec[k] = hidden[k];
    }
    __syncthreads();
    int wave = tid >> 6, lane = tid & 63;
    int rbase = (is_gi ? b : b - 384) * 16 + wave * 4;
    const float* W    = is_gi ? W_ih : W_hh;
    const float* bias = is_gi ? b_ih : b_hh;
    int K  = is_gi ? GIN : H;
    int K4 = K >> 2;                       // 576 or 512
    const float4* v4 = (const float4*)vec;
    const float4* w0 = (const float4*)(W + (long)(rbase + 0) * K);
    const float4* w1 = (const float4*)(W + (long)(rbase + 1) * K);
    const float4* w2 = (const float4*)(W + (long)(rbase + 2) * K);
    const float4* w3 = (const float4*)(W + (long)(rbase + 3) * K);
    float s0 = 0.f, s1 = 0.f, s2 = 0.f, s3 = 0.f;
    int i = lane;
    for (; i + 64 < K4; i += 128) {
        int j = i + 64;
        float4 a0  = v4[i],  a1  = v4[j];
        float4 b00 = w0[i],  b01 = w0[j];
        float4 b10 = w1[i],  b11 = w1[j];
        float4 b20 = w2[i],  b21 = w2[j];
        float4 b30 = w3[i],  b31 = w3[j];
        s0 += dot4(a0, b00) + dot4(a1, b01);
        s1 += dot4(a0, b10) + dot4(a1, b11);
        s2 += dot4(a0, b20) + dot4(a1, b21);
        s3 += dot4(a0, b30) + dot4(a1, b31);
    }
    if (i < K4) {   // gi remainder (K4=576 is odd multiple of 64)
        float4 a0 = v4[i];
        s0 += dot4(a0, w0[i]);
        s1 += dot4(a0, w1[i]);
        s2 += dot4(a0, w2[i]);
        s3 += dot4(a0, w3[i]);
    }
    s0 = wave_reduce(s0);
    s1 = wave_reduce(s1);
    s2 = wave_reduce(s2);
    s3 = wave_reduce(s3);
    float* dst = ws + (is_gi ? GI_OFF : GH_OFF);
    if (lane == 0) {
        dst[rbase + 0] = s0 + bias[rbase + 0];
        dst[rbase + 1] = s1 + bias[rbase + 1];
        dst[rbase + 2] = s2 + bias[rbase + 2];
        dst[rbase + 3] = s3 + bias[rbase + 3];
    }
}

// K3: gates -> h_new (block 0 writes it) ; out = h_new @ Wd^T + bd
__global__ __launch_bounds__(256) void k_out(
        const float* __restrict__ hidden,
        const float* __restrict__ Wd, const float* __restrict__ bd,
        const float* __restrict__ ws,
        float* __restrict__ d_out) {
    __shared__ __align__(16) float hn[H];
    int tid = threadIdx.x;
    const float* gi = ws + GI_OFF;
    const float* gh = ws + GH_OFF;
    for (int i = tid; i < H; i += 256) {
        float r = sigmoidf(gi[i] + gh[i]);
        float z = sigmoidf(gi[H + i] + gh[H + i]);
        float n = tanhf(gi[2 * H + i] + r * gh[2 * H + i]);
        float v = (1.f - z) * n + z * hidden[i];
        hn[i] = v;
        if (blockIdx.x == 0) d_out[OO + i] = v;
    }
    __syncthreads();
    int wave = tid >> 6, lane = tid & 63;
    int row = blockIdx.x * 4 + wave;     // 32*4 = 128 rows
    const float4* h4 = (const float4*)hn;
    const float4* w4 = (const float4*)(Wd + (long)row * H);
    float sum = 0.f;
#pragma unroll
    for (int i = 0; i < 8; ++i) {
        float4 a = h4[lane + i * 64];
        float4 c = w4[lane + i * 64];
        sum += dot4(a, c);
    }
    sum = wave_reduce(sum);
    if (lane == 0) d_out[row] = sum + bd[row];
}

extern "C" void kernel_launch(void* const* d_in, const int* in_sizes, int n_in,
                              void* d_out, int out_size, void* d_ws, size_t ws_size,
                              hipStream_t stream) {
    const int*   inp    = (const int*)d_in[0];
    const float* hidden = (const float*)d_in[1];
    const float* stack  = (const float*)d_in[2];
    const float* emb    = (const float*)d_in[3];
    const float* Wc     = (const float*)d_in[4];
    const float* bc     = (const float*)d_in[5];
    const float* Ws     = (const float*)d_in[6];
    const float* bs     = (const float*)d_in[7];
    const float* W_ih   = (const float*)d_in[8];
    const float* b_ih   = (const float*)d_in[9];
    const float* W_hh   = (const float*)d_in[10];
    const float* b_hh   = (const float*)d_in[11];
    const float* Wd     = (const float*)d_in[12];
    const float* bd     = (const float*)d_in[13];
    float* out = (float*)d_out;
    float* ws  = (float*)d_ws;

    k_stack<<<114, 256, 0, stream>>>(hidden, stack, Wc, bc, Ws, bs, ws, out + OO + H);
    k_gemv<<<768, 256, 0, stream>>>(hidden, emb, inp, W_ih, b_ih, W_hh, b_hh, ws);
    k_out<<<32, 256, 0, stream>>>(hidden, Wd, bd, ws, out);
}